// Round 3
// baseline (83.830 us; speedup 1.0000x reference)
//
#include <hip/hip_runtime.h>
#include <hip/hip_bf16.h>
#include <math.h>

// Channel attention: x (2,16,16,16,64) fp32 -> B=2, N=4096, C=64.
// out = gamma * softmax(QQ^T) Q + x.
// v17: fix the REAL bottleneck (model finally closes): v14/v16's KT/VT rows
// were 128 B = the 32-bank period, so every b128 fragment read was 8-way
// bank-conflicted (bank = chunk only; row never enters). 16 waves x 8 iters
// x 18 reads x ~35cyc ~= the observed ~22us. Fix: 64-B rows everywhere --
// K split into KL/KH (32keys x 32ch), VT 64ch x 32keys, PB 16x32 -- with
// chunk swizzle f(row)=(row>>1)&3 => each b128 is a bijection over its 1KB
// subtile => conflict-free. Also: KVBLK=32 + S=16 => 2048 blocks, LDS 20KB
// => 8 blocks/CU = 32 waves/CU (grid capped occupancy at 41% before).
// Depth-2 counted vmcnt(2) pipeline + setprio retained from v16.
// Fixed harness floor: ~42us d_ws re-poison fill inside the timed window.

#define NN 4096
#define CC 64
#define LOG2E 1.4426950408889634f

typedef __attribute__((ext_vector_type(4))) float f32x4;
typedef __attribute__((ext_vector_type(8))) short bf16x8;
typedef __attribute__((ext_vector_type(4))) short bf16x4;
typedef unsigned short u16;
typedef __attribute__((ext_vector_type(4))) u16 u16x4;
typedef __attribute__((ext_vector_type(2))) unsigned u32x2;

__device__ inline u16 f2bf(float f) {  // RNE
  union { float f; unsigned u; } v; v.f = f;
  unsigned r = (v.u + 0x7fffu + ((v.u >> 16) & 1u)) >> 16;
  return (u16)r;
}
__device__ inline float bf2f(short h) {
  union { unsigned u; float f; } v;
  v.u = ((unsigned)(unsigned short)h) << 16;
  return v.f;
}
__device__ inline unsigned fbits(float f) {
  union { float f; unsigned u; } v; v.f = f;
  return v.u;
}
__device__ inline bf16x8 cvt8(f32x4 a, f32x4 b) {
  bf16x8 r;
  r[0] = (short)f2bf(a[0]); r[1] = (short)f2bf(a[1]);
  r[2] = (short)f2bf(a[2]); r[3] = (short)f2bf(a[3]);
  r[4] = (short)f2bf(b[0]); r[5] = (short)f2bf(b[1]);
  r[6] = (short)f2bf(b[2]); r[7] = (short)f2bf(b[3]);
  return r;
}

// ---------------------------------------------------------------------------
// Prep: x -> bf16 Qb[b][n][c] and Vt2[b][n/64][c][n%64]. 512 blocks x 256.
// ---------------------------------------------------------------------------
__global__ __launch_bounds__(256) void prep_kernel(const float* __restrict__ x,
                                                   u16* __restrict__ Qb,
                                                   u16* __restrict__ Vt) {
  __shared__ u16 t[64][20];
  int b = blockIdx.x >> 8;
  int n0 = (blockIdx.x & 255) << 4;  // 16-row tile
  const f32x4* x4 = (const f32x4*)(x + ((size_t)b * NN + n0) * CC);
  u16* qb = Qb + ((size_t)b * NN + n0) * CC;
  {
    int idx4 = threadIdx.x;          // 256 f32x4 = 16 rows x 16 groups
    int i = idx4 >> 4, cg = idx4 & 15;
    f32x4 v = x4[idx4];
    u16x4 h;
    h[0] = f2bf(v[0]); h[1] = f2bf(v[1]); h[2] = f2bf(v[2]); h[3] = f2bf(v[3]);
    *(u16x4*)(qb + (size_t)i * CC + cg * 4) = h;
    t[cg * 4 + 0][i] = h[0]; t[cg * 4 + 1][i] = h[1];
    t[cg * 4 + 2][i] = h[2]; t[cg * 4 + 3][i] = h[3];
  }
  __syncthreads();
  int kb = n0 >> 6, kw0 = n0 & 63;   // 64-key block / offset within it
  {
    int idx4 = threadIdx.x;          // 256 u16x4 = 64 c x 4 i-groups
    int c = idx4 >> 2, i4 = (idx4 & 3) * 4;
    u16x4 h = *(const u16x4*)(&t[c][i4]);
    *(u16x4*)(Vt + (((size_t)b * (NN / 64) + kb) * 64 + c) * 64 + kw0 + i4) = h;
  }
}

// ---------------------------------------------------------------------------
// Split flash v17: block = 4 waves x 16 rows = 64 rows; S=16 key-slices,
// KVBLK=32. All LDS tiles have 64-B rows + f(row)=(row>>1)&3 chunk swizzle
// => conflict-free b128 fragment reads. 20KB LDS => 8 blocks/CU.
// ---------------------------------------------------------------------------
template <int S>
__global__ __launch_bounds__(256, 8) void attn_split(
    const u16* __restrict__ Qb, const u16* __restrict__ Vt,
    u16* __restrict__ Opart, float* __restrict__ lpart) {
  constexpr int KPS = NN / S;        // 256
  constexpr int ITERS = KPS / 32;    // 8
  const int w = threadIdx.x >> 6;    // 0..3
  const int lane = threadIdx.x & 63;
  const int quad = lane >> 4, col = lane & 15;
  const int blk = blockIdx.x;        // [0, 2*64*S)
  const int b = blk / (64 * S);
  const int rg = (blk / S) & 63;
  const int s = blk % S;

  __shared__ u16 KL[2][32 * 32];     // 4 KB: K keys x ch 0..31, 64B rows
  __shared__ u16 KH[2][32 * 32];     // 4 KB: K keys x ch 32..63
  __shared__ u16 VT[2][64 * 32];     // 8 KB: V^T ch x 32 keys, 64B rows
  __shared__ u16 PB[4][16 * 32];     // 4 KB: per-wave P, 64B rows

  const u16* Qbase = Qb + (size_t)b * NN * CC;
  const u16* Vbase = Vt + (size_t)b * NN * CC;  // [NN/64][64][64]
  const int row0 = rg * 64 + w * 16;

  // --- Q B-frag (pre-scaled by log2e); m = diag of scaled S (scalar/lane) ---
  bf16x8 qs0, qs1;
  float m_sc;
  {
    const u16* qp = Qbase + (size_t)(row0 + col) * CC + quad * 8;
    bf16x8 r0 = *(const bf16x8*)qp;
    bf16x8 r1 = *(const bf16x8*)(qp + 32);
    float msum = 0.f;
#pragma unroll
    for (int j = 0; j < 8; ++j) {
      float a0 = bf2f(r0[j]), a1 = bf2f(r1[j]);
      u16 h0 = f2bf(a0 * LOG2E), h1 = f2bf(a1 * LOG2E);
      qs0[j] = (short)h0; qs1[j] = (short)h1;
      msum += bf2f((short)h0) * a0 + bf2f((short)h1) * a1;
    }
    msum += __shfl_xor(msum, 16);
    msum += __shfl_xor(msum, 32);  // every lane: full diag for qrow=col
    m_sc = msum;
  }

  f32x4 zero = {0.f, 0.f, 0.f, 0.f};
  f32x4 acc[4] = {zero, zero, zero, zero};
  f32x4 accl = zero;                           // l row-sums via ones-B MFMA
  f32x4 cinit = {-m_sc, -m_sc, -m_sc, -m_sc};  // S - m out of the matrix pipe
  bf16x8 onesb;
#pragma unroll
  for (int j = 0; j < 8; ++j) onesb[j] = (short)0x3F80;  // bf16 1.0

  // --- staging geometry (per tile: K = 4KB as lo/hi halves, V^T = 4KB) ---
  // wave w: K part = keys (w&1)*16..+16 of ch half (w>>1); V part = ch rows
  // w*16..+16. Lane l: row base + (l>>2), chunk slot l&3, source logical
  // chunk (l&3)^((l>>3)&3)  [f(row) = (row>>1)&3].
  const int swz = (lane & 3) ^ ((lane >> 3) & 3);
  const int krow = (w & 1) * 16 + (lane >> 2);
  const int kch = (w >> 1) * 32;
  const int vrow = w * 16 + (lane >> 2);
  const u16* ksrc0 = Qbase + (size_t)(s * KPS + krow) * CC + kch + swz * 8;
  const u16* vsrc0 = Vbase + (size_t)(s * (KPS >> 6)) * 4096 + (size_t)vrow * 64 + swz * 8;
  u16* kdst = ((w >> 1) ? &KH[0][0] : &KL[0][0]) + (w & 1) * (16 * 32);
  u16* vdst = &VT[0][0] + w * (16 * 32);

#define STAGE(p, it)                                                          \
  {                                                                           \
    __builtin_amdgcn_global_load_lds(                                         \
        (const __attribute__((address_space(1))) unsigned*)(ksrc0 + (size_t)(it) * (32 * CC)), \
        (__attribute__((address_space(3))) unsigned*)(kdst + (p) * (32 * 32)),\
        16, 0, 0);                                                            \
    __builtin_amdgcn_global_load_lds(                                         \
        (const __attribute__((address_space(1))) unsigned*)(vsrc0 + ((it) >> 1) * 4096 + ((it) & 1) * 32), \
        (__attribute__((address_space(3))) unsigned*)(vdst + (p) * (64 * 32)),\
        16, 0, 0);                                                            \
  }

  STAGE(0, 0)                        // 2 gll outstanding
  STAGE(1, 1)                        // 4 outstanding
  const int cp = (col >> 1) & 3;     // f(row) for all fragment rows (row=col)
  u16* PBw = &PB[w][0];

#pragma unroll
  for (int i = 0; i < ITERS; ++i) {
    // tile i's 2 gll done; tile i+1's 2 stay in flight (never drain mid-loop)
    if (i + 1 < ITERS)
      asm volatile("s_waitcnt vmcnt(2)" ::: "memory");
    else
      asm volatile("s_waitcnt vmcnt(0)" ::: "memory");
    __builtin_amdgcn_sched_barrier(0);
    __builtin_amdgcn_s_barrier();    // all waves: tile i in LDS
    __builtin_amdgcn_sched_barrier(0);
    const int p = i & 1;

    // --- QK^T (S^T form: A=K, B=Q), C-init = -m_sc ---
    f32x4 sx[2];
    __builtin_amdgcn_s_setprio(1);
#pragma unroll
    for (int t = 0; t < 2; ++t) {
      bf16x8 ka = *(const bf16x8*)&KL[p][(t * 16 + col) * 32 + (quad ^ cp) * 8];
      bf16x8 kb = *(const bf16x8*)&KH[p][(t * 16 + col) * 32 + (quad ^ cp) * 8];
      sx[t] = __builtin_amdgcn_mfma_f32_16x16x32_bf16(ka, qs0, cinit, 0, 0, 0);
      sx[t] = __builtin_amdgcn_mfma_f32_16x16x32_bf16(kb, qs1, sx[t], 0, 0, 0);
    }
    __builtin_amdgcn_s_setprio(0);
    // --- exp2 + swizzled packed P-write (key t*16+quad*4+r) ---
#pragma unroll
    for (int t = 0; t < 2; ++t) {
      f32x4 pv;
#pragma unroll
      for (int r = 0; r < 4; ++r) pv[r] = exp2f(sx[t][r]);
      u32x2 d;
      d[0] = __builtin_amdgcn_perm(fbits(pv[1]), fbits(pv[0]), 0x07060302u);
      d[1] = __builtin_amdgcn_perm(fbits(pv[3]), fbits(pv[2]), 0x07060302u);
      *(u32x2*)&PBw[col * 32 + ((t * 2 + (quad >> 1)) ^ cp) * 8 + (quad & 1) * 4] = d;
    }
    // --- P A-frag (per-wave DS in-order; swizzled chunk addressing) ---
    bf16x8 pf0 = *(const bf16x8*)&PBw[col * 32 + (quad ^ cp) * 8];
    __builtin_amdgcn_s_setprio(1);
    // l += rowsum(P) on the matrix pipe
    accl = __builtin_amdgcn_mfma_f32_16x16x32_bf16(pf0, onesb, accl, 0, 0, 0);
    // --- PV: O[16][64] += P[16][32] * V[32][64] ---
#pragma unroll
    for (int cg = 0; cg < 4; ++cg) {
      bf16x8 va = *(const bf16x8*)&VT[p][(cg * 16 + col) * 32 + (quad ^ cp) * 8];
      acc[cg] = __builtin_amdgcn_mfma_f32_16x16x32_bf16(pf0, va, acc[cg], 0, 0, 0);
    }
    __builtin_amdgcn_s_setprio(0);
    // all waves done reading buffer p before tile i+2 overwrites it
    __builtin_amdgcn_sched_barrier(0);
    __builtin_amdgcn_s_barrier();
    __builtin_amdgcn_sched_barrier(0);
    if (i + 2 < ITERS) STAGE(p, i + 2)
  }
#undef STAGE

  // --- write partials; accl[r] = l for row quad*4+r (any col) ---
  size_t pbase = (((size_t)(b * 64 + rg)) * S + s) * (64 * 64);
  size_t lbase = (((size_t)(b * 64 + rg)) * S + s) * 64;
  if (col == 0) {
#pragma unroll
    for (int r = 0; r < 4; ++r) lpart[lbase + w * 16 + quad * 4 + r] = accl[r];
  }
#pragma unroll
  for (int r = 0; r < 4; ++r) {
    int lr = w * 16 + quad * 4 + r;
    size_t o = pbase + (size_t)lr * 64;
    Opart[o + col]      = f2bf(acc[0][r]);
    Opart[o + col + 16] = f2bf(acc[1][r]);
    Opart[o + col + 32] = f2bf(acc[2][r]);
    Opart[o + col + 48] = f2bf(acc[3][r]);
  }
}

// ---------------------------------------------------------------------------
// Epilogue: out = gamma * (sum_s O)/(sum_s l) + x. 512 blocks x 256 threads.
// ---------------------------------------------------------------------------
template <int S>
__global__ __launch_bounds__(256) void epi_kernel(
    const float* __restrict__ x, const float* __restrict__ gamma,
    const u16* __restrict__ Opart, const float* __restrict__ lpart,
    float* __restrict__ out) {
  int t = blockIdx.x * 256 + threadIdx.x;  // [0, B*NN*16)
  int cg = t & 15;
  int n = (t >> 4) & (NN - 1);
  int b = t >> 16;
  int rb = n >> 6, lr = n & 63;
  size_t obase = ((size_t)(b * 64 + rb) * S) * 4096 + (size_t)lr * 64 + cg * 4;
  size_t lbase = ((size_t)(b * 64 + rb) * S) * 64 + lr;
  f32x4 sO = {0.f, 0.f, 0.f, 0.f};
  float sL = 0.f;
#pragma unroll
  for (int s = 0; s < S; ++s) {
    u16x4 o4 = *(const u16x4*)(Opart + obase + (size_t)s * 4096);
    sL += lpart[lbase + s * 64];
    sO[0] += bf2f((short)o4[0]); sO[1] += bf2f((short)o4[1]);
    sO[2] += bf2f((short)o4[2]); sO[3] += bf2f((short)o4[3]);
  }
  size_t xi = (((size_t)b * NN + n) * CC + cg * 4);
  f32x4 xv = *(const f32x4*)(x + xi);
  float g = gamma[0], inv = 1.f / sL;
  f32x4 ov;
#pragma unroll
  for (int j = 0; j < 4; ++j) ov[j] = g * (sO[j] * inv) + xv[j];
  *(f32x4*)(((float*)out) + xi) = ov;
}

// ---------------------------------------------------------------------------
// Tier B (2MB <= ws): single-kernel path. Tier C: workspace-free.
// ---------------------------------------------------------------------------
template <int WPB>
__global__ __launch_bounds__(WPB * 64, 4) void attn_fast(
    const float* __restrict__ x, const float* __restrict__ gamma,
    const u16* __restrict__ Qb, const u16* __restrict__ Vt,
    float* __restrict__ out) {
  const int w = threadIdx.x >> 6;
  const int lane = threadIdx.x & 63;
  const int quad = lane >> 4, col = lane & 15;
  const int b = blockIdx.x >> 8;
  const int tile = (blockIdx.x & 255) << 4;

  extern __shared__ char smem[];
  float* Osh = (float*)smem;
  float* lsh = Osh + WPB * 1024;
  u16* pl = (u16*)(lsh + WPB * 16) + w * 2176;

  const size_t xoff = (size_t)b * NN * CC;
  const u16* Qbase = Qb + xoff;
  const u16* Vbase = Vt + xoff;

  bf16x8 qf0 = *(const bf16x8*)(Qbase + (size_t)(tile + col) * CC + quad * 8);
  bf16x8 qf1 = *(const bf16x8*)(Qbase + (size_t)(tile + col) * CC + 32 + quad * 8);

  float msum = 0.f;
#pragma unroll
  for (int j = 0; j < 8; ++j) {
    float a = bf2f(qf0[j]), c = bf2f(qf1[j]);
    msum += a * a + c * c;
  }
  msum += __shfl_xor(msum, 16);
  msum += __shfl_xor(msum, 32);
  float m_i[4];
#pragma unroll
  for (int r = 0; r < 4; ++r) m_i[r] = __shfl(msum, quad * 4 + r);

  f32x4 zero = {0.f, 0.f, 0.f, 0.f};
  f32x4 acc[4] = {zero, zero, zero, zero};
  float l_i[4] = {0.f, 0.f, 0.f, 0.f};

  const int k0 = w * (NN / WPB);
#pragma unroll 2
  for (int kt = k0; kt < k0 + NN / WPB; kt += 64) {
    u16* plc = pl + ((kt >> 6) & 1) * 1088;
    f32x4 sx[4];
#pragma unroll
    for (int t = 0; t < 4; ++t) {
      const u16* kp = Qbase + (size_t)(kt + t * 16 + col) * CC + quad * 8;
      bf16x8 ka = *(const bf16x8*)kp;
      bf16x8 kb = *(const bf16x8*)(kp + 32);
      sx[t] = __builtin_amdgcn_mfma_f32_16x16x32_bf16(qf0, ka, zero, 0, 0, 0);
      sx[t] = __builtin_amdgcn_mfma_f32_16x16x32_bf16(qf1, kb, sx[t], 0, 0, 0);
    }
#pragma unroll
    for (int t = 0; t < 4; ++t) {
#pragma unroll
      for (int r = 0; r < 4; ++r) {
        float p = __expf(sx[t][r] - m_i[r]);
        l_i[r] += p;
        plc[(quad * 4 + r) * 68 + t * 16 + col] = f2bf(p);
      }
    }
    bf16x8 pf0 = *(const bf16x8*)(plc + col * 68 + quad * 8);
    bf16x8 pf1 = *(const bf16x8*)(plc + col * 68 + 32 + quad * 8);
#pragma unroll
    for (int cg = 0; cg < 4; ++cg) {
      const u16* vp = Vbase + (((size_t)(kt >> 6)) * 64 + cg * 16 + col) * 64 + quad * 8;
      bf16x8 v0 = *(const bf16x8*)vp;
      bf16x8 v1 = *(const bf16x8*)(vp + 32);
      acc[cg] = __builtin_amdgcn_mfma_f32_16x16x32_bf16(pf0, v0, acc[cg], 0, 0, 0);
      acc[cg] = __builtin_amdgcn_mfma_f32_16x16x32_bf16(pf1, v1, acc[cg], 0, 0, 0);
    }
  }

#pragma unroll
  for (int r = 0; r < 4; ++r)
#pragma unroll
    for (int off = 1; off < 16; off <<= 1) l_i[r] += __shfl_xor(l_i[r], off, 16);
#pragma unroll
  for (int r = 0; r < 4; ++r) {
    int row = quad * 4 + r;
    Osh[(w * 16 + row) * 64 + col]      = acc[0][r];
    Osh[(w * 16 + row) * 64 + col + 16] = acc[1][r];
    Osh[(w * 16 + row) * 64 + col + 32] = acc[2][r];
    Osh[(w * 16 + row) * 64 + col + 48] = acc[3][r];
    if (col == 0) lsh[w * 16 + row] = l_i[r];
  }
  __syncthreads();

  float g = gamma[0];
  for (int row = w; row < 16; row += WPB) {
    float L = 0.f, val = 0.f;
#pragma unroll
    for (int w2 = 0; w2 < WPB; ++w2) {
      L += lsh[w2 * 16 + row];
      val += Osh[(w2 * 16 + row) * 64 + lane];
    }
    size_t o = xoff + (size_t)(tile + row) * CC + lane;
    out[o] = g * (val / L) + x[o];
  }
}

template <int WPB>
__global__ __launch_bounds__(512) void attn_fb(const float* __restrict__ x,
                                               const float* __restrict__ gamma,
                                               float* __restrict__ out) {
  const int w = threadIdx.x >> 6;
  const int lane = threadIdx.x & 63;
  const int quad = lane >> 4, col = lane & 15;
  const int b = blockIdx.x >> 8;
  const int tile = (blockIdx.x & 255) << 4;

  extern __shared__ char smem[];
  float* Osh = (float*)smem;
  float* msh = Osh + WPB * 1024;
  float* lsh = msh + WPB * 16;
  u16* pl = (u16*)(lsh + WPB * 16) + w * 768;
  u16* vt = (u16*)(lsh + WPB * 16) + WPB * 768 + w * 2176;

  const size_t xoff = (size_t)b * NN * CC;
  const f32x4* x4 = (const f32x4*)(x + xoff);

  bf16x8 qf0, qf1;
  {
    int ri = (tile + col) * 16 + quad * 2;
    qf0 = cvt8(x4[ri], x4[ri + 1]);
    qf1 = cvt8(x4[ri + 8], x4[ri + 9]);
  }
  f32x4 zero = {0.f, 0.f, 0.f, 0.f};
  f32x4 acc0 = zero, acc1 = zero, acc2 = zero, acc3 = zero;
  float m_i[4], l_i[4];
#pragma unroll
  for (int r = 0; r < 4; ++r) { m_i[r] = -1e30f; l_i[r] = 0.f; }

  const int k0 = w * (NN / WPB);
  for (int kt = k0; kt < k0 + NN / WPB; kt += 32) {
    bf16x8 k00, k01, k10, k11;
    {
      int kb = (kt + col) * 16 + quad * 2;
      k00 = cvt8(x4[kb], x4[kb + 1]);
      k01 = cvt8(x4[kb + 8], x4[kb + 9]);
      k10 = cvt8(x4[kb + 256], x4[kb + 257]);
      k11 = cvt8(x4[kb + 264], x4[kb + 265]);
#pragma unroll
      for (int h = 0; h < 2; ++h) {
        bf16x8 va = h ? k10 : k00, vb = h ? k11 : k01;
        int base = (h * 16 + col) * 68 + quad * 8;
        *(bf16x4*)(vt + base) = __builtin_shufflevector(va, va, 0, 1, 2, 3);
        *(bf16x4*)(vt + base + 4) = __builtin_shufflevector(va, va, 4, 5, 6, 7);
        *(bf16x4*)(vt + base + 32) = __builtin_shufflevector(vb, vb, 0, 1, 2, 3);
        *(bf16x4*)(vt + base + 36) = __builtin_shufflevector(vb, vb, 4, 5, 6, 7);
      }
    }
    f32x4 s0 = zero, s1 = zero;
    s0 = __builtin_amdgcn_mfma_f32_16x16x32_bf16(qf0, k00, s0, 0, 0, 0);
    s0 = __builtin_amdgcn_mfma_f32_16x16x32_bf16(qf1, k01, s0, 0, 0, 0);
    s1 = __builtin_amdgcn_mfma_f32_16x16x32_bf16(qf0, k10, s1, 0, 0, 0);
    s1 = __builtin_amdgcn_mfma_f32_16x16x32_bf16(qf1, k11, s1, 0, 0, 0);

    float p0[4], p1[4], alpha[4];
#pragma unroll
    for (int r = 0; r < 4; ++r) {
      float mx = fmaxf(s0[r], s1[r]);
#pragma unroll
      for (int off = 1; off < 16; off <<= 1) mx = fmaxf(mx, __shfl_xor(mx, off, 16));
      float mn = fmaxf(m_i[r], mx);
      alpha[r] = __expf(m_i[r] - mn);
      p0[r] = __expf(s0[r] - mn);
      p1[r] = __expf(s1[r] - mn);
      float rs = p0[r] + p1[r];
#pragma unroll
      for (int off = 1; off < 16; off <<= 1) rs += __shfl_xor(rs, off, 16);
      l_i[r] = l_i[r] * alpha[r] + rs;
      m_i[r] = mn;
    }
#pragma unroll
    for (int r = 0; r < 4; ++r) {
      acc0[r] *= alpha[r]; acc1[r] *= alpha[r];
      acc2[r] *= alpha[r]; acc3[r] *= alpha[r];
    }
#pragma unroll
    for (int r = 0; r < 4; ++r) {
      pl[(quad * 4 + r) * 24 + col] = f2bf(p0[r]);
      pl[384 + (quad * 4 + r) * 24 + col] = f2bf(p1[r]);
    }
    bf16x8 pf = *(const bf16x8*)(pl + (quad >> 1) * 384 + col * 24 + (quad & 1) * 8);

    bf16x8 v0, v1, v2, v3;
#pragma unroll
    for (int j = 0; j < 8; ++j) {
      int rb = (quad * 8 + j) * 68 + col;
      v0[j] = (short)vt[rb];
      v1[j] = (short)vt[rb + 16];
      v2[j] = (short)vt[rb + 32];
      v3[j] = (short)vt[rb + 48];
    }
    acc0 = __builtin_amdgcn_mfma_f32_16x16x32_bf16(pf, v0, acc0, 0, 0, 0);
    acc1 = __builtin_amdgcn_mfma_f32_16x16x32_bf16(pf, v1, acc1, 0, 0, 0);
    acc2 = __builtin_amdgcn_mfma_f32_16x16x32_bf16(pf, v2, acc2, 0, 0, 0);
    acc3 = __builtin_amdgcn_mfma_f32_16x16x32_bf16(pf, v3, acc3, 0, 0, 0);
  }

#pragma unroll
  for (int r = 0; r < 4; ++r) {
    int row = quad * 4 + r;
    Osh[(w * 16 + row) * 64 + col] = acc0[r];
    Osh[(w * 16 + row) * 64 + col + 16] = acc1[r];
    Osh[(w * 16 + row) * 64 + col + 32] = acc2[r];
    Osh[(w * 16 + row) * 64 + col + 48] = acc3[r];
    if (col == 0) { msh[w * 16 + row] = m_i[r]; lsh[w * 16 + row] = l_i[r]; }
  }
  __syncthreads();

  float g = gamma[0];
  for (int row = w; row < 16; row += WPB) {
    float M = -1e30f;
#pragma unroll
    for (int w2 = 0; w2 < WPB; ++w2) M = fmaxf(M, msh[w2 * 16 + row]);
    float L = 0.f, val = 0.f;
#pragma unroll
    for (int w2 = 0; w2 < WPB; ++w2) {
      float e = __expf(msh[w2 * 16 + row] - M);
      L += lsh[w2 * 16 + row] * e;
      val += Osh[(w2 * 16 + row) * 64 + lane] * e;
    }
    size_t o = xoff + (size_t)(tile + row) * CC + lane;
    out[o] = g * (val / L) + x[o];
  }
}

extern "C" void kernel_launch(void* const* d_in, const int* in_sizes, int n_in,
                              void* d_out, int out_size, void* d_ws, size_t ws_size,
                              hipStream_t stream) {
  const float* x = (const float*)d_in[0];
  const float* gamma = (const float*)d_in[1];
  float* out = (float*)d_out;

  constexpr int S = 16;
  constexpr size_t kQV = (size_t)2 * 2 * NN * CC * sizeof(u16);         // 2 MB
  constexpr size_t kOp = (size_t)2 * 64 * S * 64 * 64 * sizeof(u16);    // 16.8 MB
  constexpr size_t kLp = (size_t)2 * 64 * S * 64 * sizeof(float);       // 512 KB
  if (ws_size >= kQV + kOp + kLp) {
    u16* Qb = (u16*)d_ws;
    u16* Vt = Qb + (size_t)2 * NN * CC;
    u16* Opart = (u16*)((char*)d_ws + kQV);
    float* lpart = (float*)((char*)d_ws + kQV + kOp);
    prep_kernel<<<512, 256, 0, stream>>>(x, Qb, Vt);
    attn_split<S><<<2 * 64 * S, 256, 0, stream>>>(Qb, Vt, Opart, lpart);
    epi_kernel<S><<<(2 * NN * 16) / 256, 256, 0, stream>>>(x, gamma, Opart, lpart, out);
  } else if (ws_size >= kQV) {
    u16* Qb = (u16*)d_ws;
    u16* Vt = Qb + (size_t)2 * NN * CC;
    prep_kernel<<<512, 256, 0, stream>>>(x, Qb, Vt);
    constexpr int SM = 8 * 1024 * 4 + 8 * 16 * 4 + 8 * 2176 * 2;  // 68096 B
    attn_fast<8><<<512, 512, SM, stream>>>(x, gamma, Qb, Vt, out);
  } else {
    constexpr int SM4 = 4 * (1024 + 32) * 4 + 4 * 768 * 2 + 4 * 2176 * 2;
    attn_fb<4><<<512, 256, SM4, stream>>>(x, gamma, out);
  }
}

// Round 4
// 82.289 us; speedup vs baseline: 1.0187x; 1.0187x over previous
//
#include <hip/hip_runtime.h>
#include <hip/hip_bf16.h>
#include <math.h>

// Channel attention: x (2,16,16,16,64) fp32 -> B=2, N=4096, C=64.
// out = gamma * softmax(QQ^T) Q + x.
// v18: attn_split rebuilt on mfma_f32_32x32x16 (1024 FLOP / 32 operand-B,
// 2x the 16x16x32 rate per LDS byte). Post-mortem v17: bank-conflict theory
// was WRONG (v16's quad^cs chunk addressing was already bank-uniform; v17's
// fix + 2x occupancy = 0 gain) -> attn is LDS-TRAFFIC-bound (~13us of pipe
// serialization at 320B/lane/64keys). v18 cuts per-lane LDS to 128B/64keys:
// 4 waves = (key-half wk x row-half wr2); QK: A=K(LDS) B=Q(reg), S^T output
// => lane holds a full P^T column => P->PV fragments built IN REGISTERS
// (cvt_pk_bf16 + shfl_xor(32)), zero P LDS traffic; PV: A=V^T(LDS) B=P^T
// (reg), partial-O over wk combined once at end via LDS f32 transpose
// (also coalesces the Opart write). l = per-lane register sum (free).
// Staging skeleton (gll 16B, pre-swizzled source, counted vmcnt(4), raw
// barrier pair, setprio) identical to the verified v16/v17 one. S=8.
// Fixed harness floor: ~42us d_ws re-poison fill inside the timed window.

#define NN 4096
#define CC 64
#define LOG2E 1.4426950408889634f

typedef __attribute__((ext_vector_type(4))) float f32x4;
typedef __attribute__((ext_vector_type(16))) float f32x16;
typedef __attribute__((ext_vector_type(8))) short bf16x8;
typedef __attribute__((ext_vector_type(4))) short bf16x4;
typedef unsigned short u16;
typedef __attribute__((ext_vector_type(4))) u16 u16x4;
typedef __attribute__((ext_vector_type(8))) u16 u16x8;
typedef __attribute__((ext_vector_type(2))) unsigned u32x2;

__device__ inline u16 f2bf(float f) {  // RNE
  union { float f; unsigned u; } v; v.f = f;
  unsigned r = (v.u + 0x7fffu + ((v.u >> 16) & 1u)) >> 16;
  return (u16)r;
}
__device__ inline float bf2f(short h) {
  union { unsigned u; float f; } v;
  v.u = ((unsigned)(unsigned short)h) << 16;
  return v.f;
}
__device__ inline unsigned fbits(float f) {
  union { float f; unsigned u; } v; v.f = f;
  return v.u;
}
__device__ inline unsigned cvtpk(float lo, float hi) {  // {bf16(lo)|bf16(hi)<<16}
  unsigned d;
  asm("v_cvt_pk_bf16_f32 %0, %1, %2" : "=v"(d) : "v"(lo), "v"(hi));
  return d;
}
__device__ inline bf16x8 cvt8(f32x4 a, f32x4 b) {
  bf16x8 r;
  r[0] = (short)f2bf(a[0]); r[1] = (short)f2bf(a[1]);
  r[2] = (short)f2bf(a[2]); r[3] = (short)f2bf(a[3]);
  r[4] = (short)f2bf(b[0]); r[5] = (short)f2bf(b[1]);
  r[6] = (short)f2bf(b[2]); r[7] = (short)f2bf(b[3]);
  return r;
}

// ---------------------------------------------------------------------------
// Prep: x -> bf16 Qb[b][n][c] and Vt2[b][n/64][c][n%64]. 512 blocks x 256.
// ---------------------------------------------------------------------------
__global__ __launch_bounds__(256) void prep_kernel(const float* __restrict__ x,
                                                   u16* __restrict__ Qb,
                                                   u16* __restrict__ Vt) {
  __shared__ u16 t[64][20];
  int b = blockIdx.x >> 8;
  int n0 = (blockIdx.x & 255) << 4;  // 16-row tile
  const f32x4* x4 = (const f32x4*)(x + ((size_t)b * NN + n0) * CC);
  u16* qb = Qb + ((size_t)b * NN + n0) * CC;
  {
    int idx4 = threadIdx.x;          // 256 f32x4 = 16 rows x 16 groups
    int i = idx4 >> 4, cg = idx4 & 15;
    f32x4 v = x4[idx4];
    u16x4 h;
    h[0] = f2bf(v[0]); h[1] = f2bf(v[1]); h[2] = f2bf(v[2]); h[3] = f2bf(v[3]);
    *(u16x4*)(qb + (size_t)i * CC + cg * 4) = h;
    t[cg * 4 + 0][i] = h[0]; t[cg * 4 + 1][i] = h[1];
    t[cg * 4 + 2][i] = h[2]; t[cg * 4 + 3][i] = h[3];
  }
  __syncthreads();
  int kb = n0 >> 6, kw0 = n0 & 63;   // 64-key block / offset within it
  {
    int idx4 = threadIdx.x;          // 256 u16x4 = 64 c x 4 i-groups
    int c = idx4 >> 2, i4 = (idx4 & 3) * 4;
    u16x4 h = *(const u16x4*)(&t[c][i4]);
    *(u16x4*)(Vt + (((size_t)b * (NN / 64) + kb) * 64 + c) * 64 + kw0 + i4) = h;
  }
}

// ---------------------------------------------------------------------------
// Split flash v18: 32x32x16 MFMA. Block = 4 waves = (wk key-half, wr2 row-
// half) over 64 rows x 64-key tiles; S key-slices. KT raw key-major + VT
// ch-major tiles (8KB each, dbuf = 32KB LDS), chunk^row&7 swizzle, gll 16B
// pre-swizzled source. P^T stays in registers. End: wk-partial combine +
// f32 LDS transpose -> coalesced bf16 Opart.
// ---------------------------------------------------------------------------
template <int S>
__global__ __launch_bounds__(256, 4) void attn_split(
    const u16* __restrict__ Qb, const u16* __restrict__ Vt,
    u16* __restrict__ Opart, float* __restrict__ lpart) {
  constexpr int KPS = NN / S;        // 512
  constexpr int ITERS = KPS / 64;    // 8
  const int lane = threadIdx.x & 63;
  const int w = threadIdx.x >> 6;    // 0..3
  const int wk = w & 1, wr2 = w >> 1;
  const int hf = lane >> 5, l31 = lane & 31, c8 = lane & 7;
  const int blk = blockIdx.x;        // [0, 2*64*S)
  const int b = blk / (64 * S);
  const int rg = (blk / S) & 63;
  const int s = blk % S;

  __shared__ __align__(16) char smem[32768];
  u16* KT = (u16*)smem;              // [2][64 keys][64 ch] 128B rows
  u16* VT = (u16*)(smem + 16384);    // [2][64 ch][64 keys]

  const u16* Qbase = Qb + (size_t)b * NN * CC;
  const u16* Vbase = Vt + (size_t)b * NN * CC;  // [NN/64][64][64]
  const int row0 = rg * 64 + wr2 * 32;

  // --- Q B-frags (pre-scaled by log2e), m = diag of scaled S (per-lane) ---
  // B-frag sl: B[k=sl*16+hf*8+j][col=l31] = Qs[row0+l31][ch]
  bf16x8 qs[4];
  float m_sc;
  {
    const u16* qp = Qbase + (size_t)(row0 + l31) * CC + hf * 8;
    float msum = 0.f;
#pragma unroll
    for (int sl = 0; sl < 4; ++sl) {
      bf16x8 r0 = *(const bf16x8*)(qp + sl * 16);
      bf16x8 t;
#pragma unroll
      for (int j = 0; j < 8; ++j) {
        float a = bf2f(r0[j]);
        u16 hs = f2bf(a * LOG2E);
        t[j] = (short)hs;
        msum += bf2f((short)hs) * a;
      }
      qs[sl] = t;
    }
    msum += __shfl_xor(msum, 32);    // partner holds the other 32 ch
    m_sc = msum;
  }

  f32x16 cinit;
#pragma unroll
  for (int r = 0; r < 16; ++r) cinit[r] = -m_sc;
  f32x16 zero16;
#pragma unroll
  for (int r = 0; r < 16; ++r) zero16[r] = 0.f;
  f32x16 acc[2] = {zero16, zero16};  // O^T partial: cg 0 = ch 0..31, cg 1 = 32..63
  float l_loc = 0.f;

  // --- staging: wave w covers rows [w*16, w*16+16) of each 64x64 tile ---
  const int g8 = lane >> 3;          // 0..7 local row in 8-row group
  const int swz = c8 ^ g8;           // pre-swizzled 16B chunk (chunk^row&7)
  const u16* kptr = Qbase + (size_t)(s * KPS + w * 16 + g8) * CC + swz * 8;
  const u16* vptr = Vbase + (size_t)(s * (KPS >> 6)) * 4096 + (size_t)(w * 16 + g8) * 64 + swz * 8;

#define STAGE(p, it)                                                          \
  {                                                                           \
    __builtin_amdgcn_global_load_lds(                                         \
        (const __attribute__((address_space(1))) unsigned*)(kptr + (size_t)(it) * 4096),       \
        (__attribute__((address_space(3))) unsigned*)&KT[(p) * 4096 + (w * 16) * 64], 16, 0, 0); \
    __builtin_amdgcn_global_load_lds(                                         \
        (const __attribute__((address_space(1))) unsigned*)(kptr + (size_t)(it) * 4096 + 512), \
        (__attribute__((address_space(3))) unsigned*)&KT[(p) * 4096 + (w * 16 + 8) * 64], 16, 0, 0); \
    __builtin_amdgcn_global_load_lds(                                         \
        (const __attribute__((address_space(1))) unsigned*)(vptr + (size_t)(it) * 4096),       \
        (__attribute__((address_space(3))) unsigned*)&VT[(p) * 4096 + (w * 16) * 64], 16, 0, 0); \
    __builtin_amdgcn_global_load_lds(                                         \
        (const __attribute__((address_space(1))) unsigned*)(vptr + (size_t)(it) * 4096 + 512), \
        (__attribute__((address_space(3))) unsigned*)&VT[(p) * 4096 + (w * 16 + 8) * 64], 16, 0, 0); \
  }

  STAGE(0, 0)                        // 4 gll outstanding
  STAGE(1, 1)                        // 8 outstanding

#pragma unroll
  for (int i = 0; i < ITERS; ++i) {
    // tile i's 4 gll done; tile i+1's 4 stay in flight (never drain mid-loop)
    if (i + 1 < ITERS)
      asm volatile("s_waitcnt vmcnt(4)" ::: "memory");
    else
      asm volatile("s_waitcnt vmcnt(0)" ::: "memory");
    __builtin_amdgcn_sched_barrier(0);
    __builtin_amdgcn_s_barrier();    // all waves: tile i in LDS
    __builtin_amdgcn_sched_barrier(0);
    const int p = i & 1;
    const u16* KTp = KT + p * 4096;
    const u16* VTp = VT + p * 4096;

    // --- QK^T (S^T form): sx[key 16-pat][qrow=l31], keys = wk-half ---
    f32x16 sx = cinit;
    __builtin_amdgcn_s_setprio(1);
#pragma unroll
    for (int sl = 0; sl < 4; ++sl) {
      bf16x8 kf = *(const bf16x8*)&KTp[(wk * 32 + l31) * 64 + ((sl * 2 + hf) ^ c8) * 8];
      sx = __builtin_amdgcn_mfma_f32_32x32x16_bf16(kf, qs[sl], sx, 0, 0, 0);
    }
    __builtin_amdgcn_s_setprio(0);

    // --- exp2 + l + in-register P^T fragments (keys (r&3)+8*(r>>2)+4*hf) ---
    float p16[16];
#pragma unroll
    for (int r = 0; r < 16; ++r) p16[r] = exp2f(sx[r]);
#pragma unroll
    for (int r = 0; r < 16; ++r) l_loc += p16[r];
    unsigned own[4][2], sh[4][2];
#pragma unroll
    for (int q = 0; q < 4; ++q) {    // quad q = keys 8q+4hf+0..3
      own[q][0] = cvtpk(p16[4 * q + 0], p16[4 * q + 1]);
      own[q][1] = cvtpk(p16[4 * q + 2], p16[4 * q + 3]);
    }
#pragma unroll
    for (int q = 0; q < 4; ++q) {
      sh[q][0] = (unsigned)__shfl_xor((int)own[q][0], 32);
      sh[q][1] = (unsigned)__shfl_xor((int)own[q][1], 32);
    }
    bf16x8 pf[2];                    // B-frag ks: keys 16ks+8hf+0..7
#pragma unroll
    for (int ks = 0; ks < 2; ++ks) {
      unsigned d0 = hf ? sh[2 * ks + 1][0] : own[2 * ks][0];
      unsigned d1 = hf ? sh[2 * ks + 1][1] : own[2 * ks][1];
      unsigned d2 = hf ? own[2 * ks + 1][0] : sh[2 * ks][0];
      unsigned d3 = hf ? own[2 * ks + 1][1] : sh[2 * ks][1];
      bf16x8 f;
      ((unsigned*)&f)[0] = d0; ((unsigned*)&f)[1] = d1;
      ((unsigned*)&f)[2] = d2; ((unsigned*)&f)[3] = d3;
      pf[ks] = f;
    }

    // --- PV (O^T form): acc[cg] += V^T[ch][key] * P^T[key][qrow] ---
    __builtin_amdgcn_s_setprio(1);
#pragma unroll
    for (int cg = 0; cg < 2; ++cg) {
#pragma unroll
      for (int ks = 0; ks < 2; ++ks) {
        bf16x8 vf = *(const bf16x8*)&VTp[(cg * 32 + l31) * 64 + ((4 * wk + 2 * ks + hf) ^ c8) * 8];
        acc[cg] = __builtin_amdgcn_mfma_f32_32x32x16_bf16(vf, pf[ks], acc[cg], 0, 0, 0);
      }
    }
    __builtin_amdgcn_s_setprio(0);
    // all waves done reading buffer p before tile i+2 overwrites it
    __builtin_amdgcn_sched_barrier(0);
    __builtin_amdgcn_s_barrier();
    __builtin_amdgcn_sched_barrier(0);
    if (i + 2 < ITERS) STAGE(p, i + 2)
  }
#undef STAGE

  // --- combine wk partials + transpose via LDS (reuses KT/VT space) ---
  l_loc += __shfl_xor(l_loc, 32);    // partner half holds other 16 keys
  float* LDSO = (float*)smem;        // [64 ch][65] padded
  float* LDSL = (float*)(smem + 64 * 65 * 4);  // [2][64]
  const int qcol = wr2 * 32 + l31;
  if (wk == 1) {
#pragma unroll
    for (int cg = 0; cg < 2; ++cg)
#pragma unroll
      for (int r = 0; r < 16; ++r) {
        int ch = cg * 32 + (r & 3) + 8 * (r >> 2) + 4 * hf;
        LDSO[ch * 65 + qcol] = acc[cg][r];
      }
  }
  if (lane < 32) LDSL[wk * 64 + qcol] = l_loc;
  __syncthreads();
  if (wk == 0) {
#pragma unroll
    for (int cg = 0; cg < 2; ++cg)
#pragma unroll
      for (int r = 0; r < 16; ++r) {
        int ch = cg * 32 + (r & 3) + 8 * (r >> 2) + 4 * hf;
        LDSO[ch * 65 + qcol] += acc[cg][r];
      }
  }
  __syncthreads();

  size_t pbase = (((size_t)(b * 64 + rg)) * S + s) * 4096;
  size_t lbase = (((size_t)(b * 64 + rg)) * S + s) * 64;
  {
    int row = threadIdx.x >> 2;      // 0..63 (q-row)
    int cq = threadIdx.x & 3;        // 16-ch chunk
    u16x8 o0, o1;
#pragma unroll
    for (int j = 0; j < 8; ++j) {
      o0[j] = f2bf(LDSO[(cq * 16 + j) * 65 + row]);
      o1[j] = f2bf(LDSO[(cq * 16 + 8 + j) * 65 + row]);
    }
    *(u16x8*)(Opart + pbase + (size_t)row * 64 + cq * 16) = o0;
    *(u16x8*)(Opart + pbase + (size_t)row * 64 + cq * 16 + 8) = o1;
  }
  if (threadIdx.x < 64)
    lpart[lbase + threadIdx.x] = LDSL[threadIdx.x] + LDSL[64 + threadIdx.x];
}

// ---------------------------------------------------------------------------
// Epilogue: out = gamma * (sum_s O)/(sum_s l) + x. 512 blocks x 256 threads.
// ---------------------------------------------------------------------------
template <int S>
__global__ __launch_bounds__(256) void epi_kernel(
    const float* __restrict__ x, const float* __restrict__ gamma,
    const u16* __restrict__ Opart, const float* __restrict__ lpart,
    float* __restrict__ out) {
  int t = blockIdx.x * 256 + threadIdx.x;  // [0, B*NN*16)
  int cg = t & 15;
  int n = (t >> 4) & (NN - 1);
  int b = t >> 16;
  int rb = n >> 6, lr = n & 63;
  size_t obase = ((size_t)(b * 64 + rb) * S) * 4096 + (size_t)lr * 64 + cg * 4;
  size_t lbase = ((size_t)(b * 64 + rb) * S) * 64 + lr;
  f32x4 sO = {0.f, 0.f, 0.f, 0.f};
  float sL = 0.f;
#pragma unroll
  for (int s = 0; s < S; ++s) {
    u16x4 o4 = *(const u16x4*)(Opart + obase + (size_t)s * 4096);
    sL += lpart[lbase + s * 64];
    sO[0] += bf2f((short)o4[0]); sO[1] += bf2f((short)o4[1]);
    sO[2] += bf2f((short)o4[2]); sO[3] += bf2f((short)o4[3]);
  }
  size_t xi = (((size_t)b * NN + n) * CC + cg * 4);
  f32x4 xv = *(const f32x4*)(x + xi);
  float g = gamma[0], inv = 1.f / sL;
  f32x4 ov;
#pragma unroll
  for (int j = 0; j < 4; ++j) ov[j] = g * (sO[j] * inv) + xv[j];
  *(f32x4*)(((float*)out) + xi) = ov;
}

// ---------------------------------------------------------------------------
// Tier B (2MB <= ws): single-kernel path. Tier C: workspace-free.
// ---------------------------------------------------------------------------
template <int WPB>
__global__ __launch_bounds__(WPB * 64, 4) void attn_fast(
    const float* __restrict__ x, const float* __restrict__ gamma,
    const u16* __restrict__ Qb, const u16* __restrict__ Vt,
    float* __restrict__ out) {
  const int w = threadIdx.x >> 6;
  const int lane = threadIdx.x & 63;
  const int quad = lane >> 4, col = lane & 15;
  const int b = blockIdx.x >> 8;
  const int tile = (blockIdx.x & 255) << 4;

  extern __shared__ char smem[];
  float* Osh = (float*)smem;
  float* lsh = Osh + WPB * 1024;
  u16* pl = (u16*)(lsh + WPB * 16) + w * 2176;

  const size_t xoff = (size_t)b * NN * CC;
  const u16* Qbase = Qb + xoff;
  const u16* Vbase = Vt + xoff;

  bf16x8 qf0 = *(const bf16x8*)(Qbase + (size_t)(tile + col) * CC + quad * 8);
  bf16x8 qf1 = *(const bf16x8*)(Qbase + (size_t)(tile + col) * CC + 32 + quad * 8);

  float msum = 0.f;
#pragma unroll
  for (int j = 0; j < 8; ++j) {
    float a = bf2f(qf0[j]), c = bf2f(qf1[j]);
    msum += a * a + c * c;
  }
  msum += __shfl_xor(msum, 16);
  msum += __shfl_xor(msum, 32);
  float m_i[4];
#pragma unroll
  for (int r = 0; r < 4; ++r) m_i[r] = __shfl(msum, quad * 4 + r);

  f32x4 zero = {0.f, 0.f, 0.f, 0.f};
  f32x4 acc[4] = {zero, zero, zero, zero};
  float l_i[4] = {0.f, 0.f, 0.f, 0.f};

  const int k0 = w * (NN / WPB);
#pragma unroll 2
  for (int kt = k0; kt < k0 + NN / WPB; kt += 64) {
    u16* plc = pl + ((kt >> 6) & 1) * 1088;
    f32x4 sx[4];
#pragma unroll
    for (int t = 0; t < 4; ++t) {
      const u16* kp = Qbase + (size_t)(kt + t * 16 + col) * CC + quad * 8;
      bf16x8 ka = *(const bf16x8*)kp;
      bf16x8 kb = *(const bf16x8*)(kp + 32);
      sx[t] = __builtin_amdgcn_mfma_f32_16x16x32_bf16(qf0, ka, zero, 0, 0, 0);
      sx[t] = __builtin_amdgcn_mfma_f32_16x16x32_bf16(qf1, kb, sx[t], 0, 0, 0);
    }
#pragma unroll
    for (int t = 0; t < 4; ++t) {
#pragma unroll
      for (int r = 0; r < 4; ++r) {
        float p = __expf(sx[t][r] - m_i[r]);
        l_i[r] += p;
        plc[(quad * 4 + r) * 68 + t * 16 + col] = f2bf(p);
      }
    }
    bf16x8 pf0 = *(const bf16x8*)(plc + col * 68 + quad * 8);
    bf16x8 pf1 = *(const bf16x8*)(plc + col * 68 + 32 + quad * 8);
#pragma unroll
    for (int cg = 0; cg < 4; ++cg) {
      const u16* vp = Vbase + (((size_t)(kt >> 6)) * 64 + cg * 16 + col) * 64 + quad * 8;
      bf16x8 v0 = *(const bf16x8*)vp;
      bf16x8 v1 = *(const bf16x8*)(vp + 32);
      acc[cg] = __builtin_amdgcn_mfma_f32_16x16x32_bf16(pf0, v0, acc[cg], 0, 0, 0);
      acc[cg] = __builtin_amdgcn_mfma_f32_16x16x32_bf16(pf1, v1, acc[cg], 0, 0, 0);
    }
  }

#pragma unroll
  for (int r = 0; r < 4; ++r)
#pragma unroll
    for (int off = 1; off < 16; off <<= 1) l_i[r] += __shfl_xor(l_i[r], off, 16);
#pragma unroll
  for (int r = 0; r < 4; ++r) {
    int row = quad * 4 + r;
    Osh[(w * 16 + row) * 64 + col]      = acc[0][r];
    Osh[(w * 16 + row) * 64 + col + 16] = acc[1][r];
    Osh[(w * 16 + row) * 64 + col + 32] = acc[2][r];
    Osh[(w * 16 + row) * 64 + col + 48] = acc[3][r];
    if (col == 0) lsh[w * 16 + row] = l_i[r];
  }
  __syncthreads();

  float g = gamma[0];
  for (int row = w; row < 16; row += WPB) {
    float L = 0.f, val = 0.f;
#pragma unroll
    for (int w2 = 0; w2 < WPB; ++w2) {
      L += lsh[w2 * 16 + row];
      val += Osh[(w2 * 16 + row) * 64 + lane];
    }
    size_t o = xoff + (size_t)(tile + row) * CC + lane;
    out[o] = g * (val / L) + x[o];
  }
}

template <int WPB>
__global__ __launch_bounds__(512) void attn_fb(const float* __restrict__ x,
                                               const float* __restrict__ gamma,
                                               float* __restrict__ out) {
  const int w = threadIdx.x >> 6;
  const int lane = threadIdx.x & 63;
  const int quad = lane >> 4, col = lane & 15;
  const int b = blockIdx.x >> 8;
  const int tile = (blockIdx.x & 255) << 4;

  extern __shared__ char smem[];
  float* Osh = (float*)smem;
  float* msh = Osh + WPB * 1024;
  float* lsh = msh + WPB * 16;
  u16* pl = (u16*)(lsh + WPB * 16) + w * 768;
  u16* vt = (u16*)(lsh + WPB * 16) + WPB * 768 + w * 2176;

  const size_t xoff = (size_t)b * NN * CC;
  const f32x4* x4 = (const f32x4*)(x + xoff);

  bf16x8 qf0, qf1;
  {
    int ri = (tile + col) * 16 + quad * 2;
    qf0 = cvt8(x4[ri], x4[ri + 1]);
    qf1 = cvt8(x4[ri + 8], x4[ri + 9]);
  }
  f32x4 zero = {0.f, 0.f, 0.f, 0.f};
  f32x4 acc0 = zero, acc1 = zero, acc2 = zero, acc3 = zero;
  float m_i[4], l_i[4];
#pragma unroll
  for (int r = 0; r < 4; ++r) { m_i[r] = -1e30f; l_i[r] = 0.f; }

  const int k0 = w * (NN / WPB);
  for (int kt = k0; kt < k0 + NN / WPB; kt += 32) {
    bf16x8 k00, k01, k10, k11;
    {
      int kb = (kt + col) * 16 + quad * 2;
      k00 = cvt8(x4[kb], x4[kb + 1]);
      k01 = cvt8(x4[kb + 8], x4[kb + 9]);
      k10 = cvt8(x4[kb + 256], x4[kb + 257]);
      k11 = cvt8(x4[kb + 264], x4[kb + 265]);
#pragma unroll
      for (int h = 0; h < 2; ++h) {
        bf16x8 va = h ? k10 : k00, vb = h ? k11 : k01;
        int base = (h * 16 + col) * 68 + quad * 8;
        *(bf16x4*)(vt + base) = __builtin_shufflevector(va, va, 0, 1, 2, 3);
        *(bf16x4*)(vt + base + 4) = __builtin_shufflevector(va, va, 4, 5, 6, 7);
        *(bf16x4*)(vt + base + 32) = __builtin_shufflevector(vb, vb, 0, 1, 2, 3);
        *(bf16x4*)(vt + base + 36) = __builtin_shufflevector(vb, vb, 4, 5, 6, 7);
      }
    }
    f32x4 s0 = zero, s1 = zero;
    s0 = __builtin_amdgcn_mfma_f32_16x16x32_bf16(qf0, k00, s0, 0, 0, 0);
    s0 = __builtin_amdgcn_mfma_f32_16x16x32_bf16(qf1, k01, s0, 0, 0, 0);
    s1 = __builtin_amdgcn_mfma_f32_16x16x32_bf16(qf0, k10, s1, 0, 0, 0);
    s1 = __builtin_amdgcn_mfma_f32_16x16x32_bf16(qf1, k11, s1, 0, 0, 0);

    float p0[4], p1[4], alpha[4];
#pragma unroll
    for (int r = 0; r < 4; ++r) {
      float mx = fmaxf(s0[r], s1[r]);
#pragma unroll
      for (int off = 1; off < 16; off <<= 1) mx = fmaxf(mx, __shfl_xor(mx, off, 16));
      float mn = fmaxf(m_i[r], mx);
      alpha[r] = __expf(m_i[r] - mn);
      p0[r] = __expf(s0[r] - mn);
      p1[r] = __expf(s1[r] - mn);
      float rs = p0[r] + p1[r];
#pragma unroll
      for (int off = 1; off < 16; off <<= 1) rs += __shfl_xor(rs, off, 16);
      l_i[r] = l_i[r] * alpha[r] + rs;
      m_i[r] = mn;
    }
#pragma unroll
    for (int r = 0; r < 4; ++r) {
      acc0[r] *= alpha[r]; acc1[r] *= alpha[r];
      acc2[r] *= alpha[r]; acc3[r] *= alpha[r];
    }
#pragma unroll
    for (int r = 0; r < 4; ++r) {
      pl[(quad * 4 + r) * 24 + col] = f2bf(p0[r]);
      pl[384 + (quad * 4 + r) * 24 + col] = f2bf(p1[r]);
    }
    bf16x8 pf = *(const bf16x8*)(pl + (quad >> 1) * 384 + col * 24 + (quad & 1) * 8);

    bf16x8 v0, v1, v2, v3;
#pragma unroll
    for (int j = 0; j < 8; ++j) {
      int rb = (quad * 8 + j) * 68 + col;
      v0[j] = (short)vt[rb];
      v1[j] = (short)vt[rb + 16];
      v2[j] = (short)vt[rb + 32];
      v3[j] = (short)vt[rb + 48];
    }
    acc0 = __builtin_amdgcn_mfma_f32_16x16x32_bf16(pf, v0, acc0, 0, 0, 0);
    acc1 = __builtin_amdgcn_mfma_f32_16x16x32_bf16(pf, v1, acc1, 0, 0, 0);
    acc2 = __builtin_amdgcn_mfma_f32_16x16x32_bf16(pf, v2, acc2, 0, 0, 0);
    acc3 = __builtin_amdgcn_mfma_f32_16x16x32_bf16(pf, v3, acc3, 0, 0, 0);
  }

#pragma unroll
  for (int r = 0; r < 4; ++r) {
    int row = quad * 4 + r;
    Osh[(w * 16 + row) * 64 + col] = acc0[r];
    Osh[(w * 16 + row) * 64 + col + 16] = acc1[r];
    Osh[(w * 16 + row) * 64 + col + 32] = acc2[r];
    Osh[(w * 16 + row) * 64 + col + 48] = acc3[r];
    if (col == 0) { msh[w * 16 + row] = m_i[r]; lsh[w * 16 + row] = l_i[r]; }
  }
  __syncthreads();

  float g = gamma[0];
  for (int row = w; row < 16; row += WPB) {
    float M = -1e30f;
#pragma unroll
    for (int w2 = 0; w2 < WPB; ++w2) M = fmaxf(M, msh[w2 * 16 + row]);
    float L = 0.f, val = 0.f;
#pragma unroll
    for (int w2 = 0; w2 < WPB; ++w2) {
      float e = __expf(msh[w2 * 16 + row] - M);
      L += lsh[w2 * 16 + row] * e;
      val += Osh[(w2 * 16 + row) * 64 + lane] * e;
    }
    size_t o = xoff + (size_t)(tile + row) * CC + lane;
    out[o] = g * (val / L) + x[o];
  }
}

extern "C" void kernel_launch(void* const* d_in, const int* in_sizes, int n_in,
                              void* d_out, int out_size, void* d_ws, size_t ws_size,
                              hipStream_t stream) {
  const float* x = (const float*)d_in[0];
  const float* gamma = (const float*)d_in[1];
  float* out = (float*)d_out;

  constexpr int S = 8;
  constexpr size_t kQV = (size_t)2 * 2 * NN * CC * sizeof(u16);         // 2 MB
  constexpr size_t kOp = (size_t)2 * 64 * S * 64 * 64 * sizeof(u16);    // 8 MB
  constexpr size_t kLp = (size_t)2 * 64 * S * 64 * sizeof(float);       // 256 KB
  if (ws_size >= kQV + kOp + kLp) {
    u16* Qb = (u16*)d_ws;
    u16* Vt = Qb + (size_t)2 * NN * CC;
    u16* Opart = (u16*)((char*)d_ws + kQV);
    float* lpart = (float*)((char*)d_ws + kQV + kOp);
    prep_kernel<<<512, 256, 0, stream>>>(x, Qb, Vt);
    attn_split<S><<<2 * 64 * S, 256, 0, stream>>>(Qb, Vt, Opart, lpart);
    epi_kernel<S><<<(2 * NN * 16) / 256, 256, 0, stream>>>(x, gamma, Opart, lpart, out);
  } else if (ws_size >= kQV) {
    u16* Qb = (u16*)d_ws;
    u16* Vt = Qb + (size_t)2 * NN * CC;
    prep_kernel<<<512, 256, 0, stream>>>(x, Qb, Vt);
    constexpr int SM = 8 * 1024 * 4 + 8 * 16 * 4 + 8 * 2176 * 2;  // 68096 B
    attn_fast<8><<<512, 512, SM, stream>>>(x, gamma, Qb, Vt, out);
  } else {
    constexpr int SM4 = 4 * (1024 + 32) * 4 + 4 * 768 * 2 + 4 * 2176 * 2;
    attn_fb<4><<<512, 256, SM4, stream>>>(x, gamma, out);
  }
}